// Round 7
// baseline (6389.231 us; speedup 1.0000x reference)
//
#include <hip/hip_runtime.h>

typedef __attribute__((ext_vector_type(8))) short short8;
typedef __attribute__((ext_vector_type(4))) float f32x4;
typedef __attribute__((ext_vector_type(4))) unsigned u32x4;

__device__ __forceinline__ unsigned short f2bf(float f) {
  unsigned int u = __float_as_uint(f);
  u = (u + 0x7fffu + ((u >> 16) & 1u)) >> 16;
  return (unsigned short)u;
}

__device__ __forceinline__ void xp_store(float* p, float v) { *p = v; }
__device__ __forceinline__ void xp_store(unsigned short* p, float v) { *p = f2bf(v); }
__device__ __forceinline__ float xp_load(const float* p) { return *p; }
__device__ __forceinline__ float xp_load(const unsigned short* p) {
  return __uint_as_float(((unsigned int)*p) << 16);
}

// ---------------- prep: pack W_x (f32 -> bf16 pairs) ----------------
__global__ void prep_wx(const float* __restrict__ W, unsigned int* __restrict__ Wx2) {
  int i = blockIdx.x * 256 + threadIdx.x;  // 1024*128 dwords
  int g = i >> 7, kk = i & 127;
  float lo = W[(size_t)g * 512 + 256 + 2 * kk];
  float hi = W[(size_t)g * 512 + 256 + 2 * kk + 1];
  Wx2[i] = (unsigned int)f2bf(lo) | ((unsigned int)f2bf(hi) << 16);
}

// ---------------- GEMM: xp[m][g] = sum_k x[m][k] * Wx[g][k] + b[g] ----------------
template <typename XPT>
__global__ __launch_bounds__(256, 4) void gemm_xp(const float* __restrict__ x,
                                                  const unsigned int* __restrict__ Wx2,
                                                  const float* __restrict__ bias,
                                                  XPT* __restrict__ xp) {
  __shared__ unsigned short As[128][40];
  __shared__ unsigned short Bs[128][40];
  const int m0 = blockIdx.y * 128, n0 = blockIdx.x * 128;
  const int tid = threadIdx.x, lane = tid & 63, w = tid >> 6;
  const int wr = w >> 1, wc = w & 1;
  const int r16 = lane & 15, kq = lane >> 4;
  f32x4 acc[4][4];
#pragma unroll
  for (int m = 0; m < 4; m++)
#pragma unroll
    for (int n = 0; n < 4; n++)
#pragma unroll
      for (int j = 0; j < 4; j++) acc[m][n][j] = 0.f;

  for (int kb = 0; kb < 256; kb += 32) {
    __syncthreads();
#pragma unroll
    for (int i = 0; i < 4; i++) {
      int idx = tid + i * 256;
      int row = idx >> 3, c4 = idx & 7;
      float4 v = *(const float4*)(x + (size_t)(m0 + row) * 256 + kb + c4 * 4);
      ushort4 s;
      s.x = f2bf(v.x); s.y = f2bf(v.y); s.z = f2bf(v.z); s.w = f2bf(v.w);
      *(ushort4*)&As[row][c4 * 4] = s;
    }
#pragma unroll
    for (int i = 0; i < 2; i++) {
      int idx = tid + i * 256;
      int row = idx >> 2, c = idx & 3;
      uint4 v = *(const uint4*)(Wx2 + (size_t)(n0 + row) * 128 + (kb >> 1) + c * 4);
      *(uint4*)&Bs[row][c * 8] = v;
    }
    __syncthreads();
    short8 a[4], bb[4];
#pragma unroll
    for (int m = 0; m < 4; m++)
      a[m] = *(const short8*)&As[wr * 64 + m * 16 + r16][kq * 8];
#pragma unroll
    for (int n = 0; n < 4; n++)
      bb[n] = *(const short8*)&Bs[wc * 64 + n * 16 + r16][kq * 8];
#pragma unroll
    for (int m = 0; m < 4; m++)
#pragma unroll
      for (int n = 0; n < 4; n++)
        acc[m][n] = __builtin_amdgcn_mfma_f32_16x16x32_bf16(a[m], bb[n], acc[m][n], 0, 0, 0);
  }
#pragma unroll
  for (int n = 0; n < 4; n++) {
    int gn = n0 + wc * 64 + n * 16 + r16;
    float bi = bias[gn];
#pragma unroll
    for (int m = 0; m < 4; m++) {
      int gm = m0 + wr * 64 + m * 16 + kq * 4;
#pragma unroll
      for (int j = 0; j < 4; j++) {
        xp_store(&xp[(size_t)(gm + j) * 1024 + gn], acc[m][n][j] + bi);
      }
    }
  }
}

// ---------------- recurrence: self-stamped h exchange + pinned weights -------------
// 4 WGs per batch; WG q owns units [q*64, q*64+64). Thread (u=tid>>3, ks=tid&7) holds
// all four gate rows of unit u over K-slice [ks*32, ks*32+32) in 32 named f32x4,
// PINNED in VGPRs by an empty asm with "+v" ties inside the loop (a reload cannot
// produce the asm's output => allocator must keep them resident; tell: VGPR>=200).
// Exchange: published dword = (bf16(h)<<16)|(t+1). Data IS the flag: producer has NO
// waits; consumer's poll IS the bulk load (each lane re-reads its 128B ks-slice line
// until all 32 stamps == t). Stamp induction: stamp t+2 is written into a slot only
// after its writer observed all stamps==t+1, i.e. after every wave's step-t reads
// retired (vmcnt(0) precedes accept, accept precedes the wave's stamp store), so 2
// slots suffice; while polling for t only {t-2, t} can appear. hbuf is memset each
// launch so stale stamps never validate (replay-safe). All ops sc0 sc1 (MALL scope,
// placement-oblivious -- R3 lesson: correctness never depends on XCD mapping).
template <typename XPT>
__global__ __launch_bounds__(512, 2) void lstm_rec(const float* __restrict__ W,
                                                   const XPT* __restrict__ xp,
                                                   float* __restrict__ out,
                                                   unsigned* __restrict__ hbuf) {
  const int tid = threadIdx.x;
  const int b = blockIdx.x & 63, q = blockIdx.x >> 6;
  const int ks = tid & 7, u = tid >> 3;
  const int gu = (q << 6) + u;

  // weights: 4 gate rows x 32-K-slice as 32 NAMED f32x4 values (128 VGPRs)
  const float* rp0 = W + (size_t)(0 * 256 + gu) * 512 + (ks << 5);
  const float* rp1 = W + (size_t)(1 * 256 + gu) * 512 + (ks << 5);
  const float* rp2 = W + (size_t)(2 * 256 + gu) * 512 + (ks << 5);
  const float* rp3 = W + (size_t)(3 * 256 + gu) * 512 + (ks << 5);
  f32x4 wA0 = *(const f32x4*)(rp0 + 0),  wA1 = *(const f32x4*)(rp0 + 4);
  f32x4 wA2 = *(const f32x4*)(rp0 + 8),  wA3 = *(const f32x4*)(rp0 + 12);
  f32x4 wA4 = *(const f32x4*)(rp0 + 16), wA5 = *(const f32x4*)(rp0 + 20);
  f32x4 wA6 = *(const f32x4*)(rp0 + 24), wA7 = *(const f32x4*)(rp0 + 28);
  f32x4 wB0 = *(const f32x4*)(rp1 + 0),  wB1 = *(const f32x4*)(rp1 + 4);
  f32x4 wB2 = *(const f32x4*)(rp1 + 8),  wB3 = *(const f32x4*)(rp1 + 12);
  f32x4 wB4 = *(const f32x4*)(rp1 + 16), wB5 = *(const f32x4*)(rp1 + 20);
  f32x4 wB6 = *(const f32x4*)(rp1 + 24), wB7 = *(const f32x4*)(rp1 + 28);
  f32x4 wC0 = *(const f32x4*)(rp2 + 0),  wC1 = *(const f32x4*)(rp2 + 4);
  f32x4 wC2 = *(const f32x4*)(rp2 + 8),  wC3 = *(const f32x4*)(rp2 + 12);
  f32x4 wC4 = *(const f32x4*)(rp2 + 16), wC5 = *(const f32x4*)(rp2 + 20);
  f32x4 wC6 = *(const f32x4*)(rp2 + 24), wC7 = *(const f32x4*)(rp2 + 28);
  f32x4 wD0 = *(const f32x4*)(rp3 + 0),  wD1 = *(const f32x4*)(rp3 + 4);
  f32x4 wD2 = *(const f32x4*)(rp3 + 8),  wD3 = *(const f32x4*)(rp3 + 12);
  f32x4 wD4 = *(const f32x4*)(rp3 + 16), wD5 = *(const f32x4*)(rp3 + 20);
  f32x4 wD6 = *(const f32x4*)(rp3 + 24), wD7 = *(const f32x4*)(rp3 + 28);

  unsigned* hb = hbuf + ((size_t)b << 9);  // 2 slots x 256 stamped dwords
  const size_t xpb = (size_t)b << 10;

  float xv0, xv1, xv2, xv3;
  {
    const XPT* xr = &xp[xpb * 1024 + gu];
    xv0 = xp_load(xr); xv1 = xp_load(xr + 256);
    xv2 = xp_load(xr + 512); xv3 = xp_load(xr + 768);
  }
  float c = 0.f, hprev = 0.f;

  for (int t = 0; t < 1024; t++) {
    // pin the 32 weight vectors in registers every iteration (zero instructions)
    asm volatile("" : "+v"(wA0), "+v"(wA1), "+v"(wA2), "+v"(wA3),
                      "+v"(wA4), "+v"(wA5), "+v"(wA6), "+v"(wA7));
    asm volatile("" : "+v"(wB0), "+v"(wB1), "+v"(wB2), "+v"(wB3),
                      "+v"(wB4), "+v"(wB5), "+v"(wB6), "+v"(wB7));
    asm volatile("" : "+v"(wC0), "+v"(wC1), "+v"(wC2), "+v"(wC3),
                      "+v"(wC4), "+v"(wC5), "+v"(wC6), "+v"(wC7));
    asm volatile("" : "+v"(wD0), "+v"(wD1), "+v"(wD2), "+v"(wD3),
                      "+v"(wD4), "+v"(wD5), "+v"(wD6), "+v"(wD7));

    u32x4 r0, r1, r2, r3, r4, r5, r6, r7;
    if (t > 0) {
      const unsigned* hs = hb + (((t - 1) & 1) << 8) + (ks << 5);
      const unsigned tpat = (unsigned)t;
      for (;;) {
        asm volatile(
            "global_load_dwordx4 %0, %8, off sc0 sc1\n\t"
            "global_load_dwordx4 %1, %8, off offset:16 sc0 sc1\n\t"
            "global_load_dwordx4 %2, %8, off offset:32 sc0 sc1\n\t"
            "global_load_dwordx4 %3, %8, off offset:48 sc0 sc1\n\t"
            "global_load_dwordx4 %4, %8, off offset:64 sc0 sc1\n\t"
            "global_load_dwordx4 %5, %8, off offset:80 sc0 sc1\n\t"
            "global_load_dwordx4 %6, %8, off offset:96 sc0 sc1\n\t"
            "global_load_dwordx4 %7, %8, off offset:112 sc0 sc1\n\t"
            "s_waitcnt vmcnt(0)"
            : "=&v"(r0), "=&v"(r1), "=&v"(r2), "=&v"(r3),
              "=&v"(r4), "=&v"(r5), "=&v"(r6), "=&v"(r7)
            : "v"(hs)
            : "memory");
        unsigned bad;
        bad  = (r0[0] ^ tpat) | (r0[1] ^ tpat) | (r0[2] ^ tpat) | (r0[3] ^ tpat);
        bad |= (r1[0] ^ tpat) | (r1[1] ^ tpat) | (r1[2] ^ tpat) | (r1[3] ^ tpat);
        bad |= (r2[0] ^ tpat) | (r2[1] ^ tpat) | (r2[2] ^ tpat) | (r2[3] ^ tpat);
        bad |= (r3[0] ^ tpat) | (r3[1] ^ tpat) | (r3[2] ^ tpat) | (r3[3] ^ tpat);
        bad |= (r4[0] ^ tpat) | (r4[1] ^ tpat) | (r4[2] ^ tpat) | (r4[3] ^ tpat);
        bad |= (r5[0] ^ tpat) | (r5[1] ^ tpat) | (r5[2] ^ tpat) | (r5[3] ^ tpat);
        bad |= (r6[0] ^ tpat) | (r6[1] ^ tpat) | (r6[2] ^ tpat) | (r6[3] ^ tpat);
        bad |= (r7[0] ^ tpat) | (r7[1] ^ tpat) | (r7[2] ^ tpat) | (r7[3] ^ tpat);
        if (__all((int)((bad & 0xFFFFu) == 0u))) break;
      }
    } else {
      r0 = r1 = r2 = r3 = r4 = r5 = r6 = r7 = (u32x4){0u, 0u, 0u, 0u};
    }

    // early issue (off critical path): previous row's out store + next xp prefetch;
    // both complete under the ~1.5kcy of compute below, so the next poll's
    // vmcnt(0) drains nothing.
    if (t > 0 && ks == 0)
      __builtin_nontemporal_store(hprev, &out[(xpb + t - 1) * 256 + gu]);
    float xn0 = 0.f, xn1 = 0.f, xn2 = 0.f, xn3 = 0.f;
    if (t < 1023) {
      const XPT* xr = &xp[(xpb + t + 1) * 1024 + gu];
      xn0 = xp_load(xr); xn1 = xp_load(xr + 256);
      xn2 = xp_load(xr + 512); xn3 = xp_load(xr + 768);
    }

    // unmask stamps -> bf16<<16 f32 values
#define UNM(H, R)                                              \
  f32x4 H = {__uint_as_float((R)[0] & 0xFFFF0000u),            \
             __uint_as_float((R)[1] & 0xFFFF0000u),            \
             __uint_as_float((R)[2] & 0xFFFF0000u),            \
             __uint_as_float((R)[3] & 0xFFFF0000u)};
    UNM(h0, r0) UNM(h1, r1) UNM(h2, r2) UNM(h3, r3)
    UNM(h4, r4) UNM(h5, r5) UNM(h6, r6) UNM(h7, r7)
#undef UNM

    float a0 = 0.f, a1 = 0.f, a2 = 0.f, a3 = 0.f;
#define FMA4(ACC, WV, HV)                 \
  ACC = fmaf((WV)[0], (HV)[0], ACC);      \
  ACC = fmaf((WV)[1], (HV)[1], ACC);      \
  ACC = fmaf((WV)[2], (HV)[2], ACC);      \
  ACC = fmaf((WV)[3], (HV)[3], ACC);
    FMA4(a0, wA0, h0) FMA4(a0, wA1, h1) FMA4(a0, wA2, h2) FMA4(a0, wA3, h3)
    FMA4(a0, wA4, h4) FMA4(a0, wA5, h5) FMA4(a0, wA6, h6) FMA4(a0, wA7, h7)
    FMA4(a1, wB0, h0) FMA4(a1, wB1, h1) FMA4(a1, wB2, h2) FMA4(a1, wB3, h3)
    FMA4(a1, wB4, h4) FMA4(a1, wB5, h5) FMA4(a1, wB6, h6) FMA4(a1, wB7, h7)
    FMA4(a2, wC0, h0) FMA4(a2, wC1, h1) FMA4(a2, wC2, h2) FMA4(a2, wC3, h3)
    FMA4(a2, wC4, h4) FMA4(a2, wC5, h5) FMA4(a2, wC6, h6) FMA4(a2, wC7, h7)
    FMA4(a3, wD0, h0) FMA4(a3, wD1, h1) FMA4(a3, wD2, h2) FMA4(a3, wD3, h3)
    FMA4(a3, wD4, h4) FMA4(a3, wD5, h5) FMA4(a3, wD6, h6) FMA4(a3, wD7, h7)
#undef FMA4
#pragma unroll
    for (int d = 1; d < 8; d <<= 1) {
      a0 += __shfl_xor(a0, d, 64);
      a1 += __shfl_xor(a1, d, 64);
      a2 += __shfl_xor(a2, d, 64);
      a3 += __shfl_xor(a3, d, 64);
    }

    float gf = a0 + xv0, gi = a1 + xv1, gg = a2 + xv2, go = a3 + xv3;
    float f = 1.f / (1.f + __expf(-gf));
    float ii = 1.f / (1.f + __expf(-gi));
    float eg = __expf(2.f * gg);
    float gt = (eg - 1.f) / (eg + 1.f);
    float o = 1.f / (1.f + __expf(-go));
    c = f * c + ii * gt;
    float ec = __expf(2.f * c);
    float tc = (ec - 1.f) / (ec + 1.f);
    float h = o * tc;

    // publish self-stamped h immediately: no waits, no separate flag
    if (ks == 0) {
      unsigned dw = ((unsigned)f2bf(h) << 16) | (unsigned)(t + 1);
      unsigned* hp = hb + ((t & 1) << 8) + gu;
      asm volatile("global_store_dword %0, %1, off sc0 sc1" ::"v"(hp), "v"(dw) : "memory");
    }

    hprev = h;
    xv0 = xn0; xv1 = xn1; xv2 = xn2; xv3 = xn3;
  }

  if (ks == 0) {
    out[(xpb + 1023) * 256 + gu] = hprev;
    out[16777216 + b * 256 + gu] = hprev;          // h_fin
    out[16777216 + 16384 + b * 256 + gu] = c;      // c_fin
  }
}

extern "C" void kernel_launch(void* const* d_in, const int* in_sizes, int n_in,
                              void* d_out, int out_size, void* d_ws, size_t ws_size,
                              hipStream_t stream) {
  (void)in_sizes; (void)n_in; (void)out_size;
  const float* x = (const float*)d_in[0];
  const float* W = (const float*)d_in[1];
  const float* bias = (const float*)d_in[2];
  float* out = (float*)d_out;
  char* ws = (char*)d_ws;

  unsigned int* Wx2 = (unsigned int*)ws;              // 524288 B
  unsigned int* hbuf = (unsigned int*)(ws + 524288);  // 131072 B (64 b x 2 x 256 dwords)
  char* xpmem = ws + 1048576;

  const size_t need32 = 1048576 + (size_t)65536 * 1024 * 4;

  hipMemsetAsync(hbuf, 0, 131072, stream);  // stale stamps must never validate
  prep_wx<<<512, 256, 0, stream>>>(W, Wx2);

  if (ws_size >= need32) {
    gemm_xp<float><<<dim3(8, 512), 256, 0, stream>>>(x, Wx2, bias, (float*)xpmem);
    lstm_rec<float><<<256, 512, 0, stream>>>(W, (const float*)xpmem, out, hbuf);
  } else {
    gemm_xp<unsigned short><<<dim3(8, 512), 256, 0, stream>>>(x, Wx2, bias,
                                                              (unsigned short*)xpmem);
    lstm_rec<unsigned short><<<256, 512, 0, stream>>>(W, (const unsigned short*)xpmem, out,
                                                      hbuf);
  }
}

// Round 8
// 2519.079 us; speedup vs baseline: 2.5363x; 2.5363x over previous
//
#include <hip/hip_runtime.h>

typedef __attribute__((ext_vector_type(8))) short short8;
typedef __attribute__((ext_vector_type(4))) float f32x4;
typedef __attribute__((ext_vector_type(4))) unsigned u32x4;

__device__ __forceinline__ unsigned short f2bf(float f) {
  unsigned int u = __float_as_uint(f);
  u = (u + 0x7fffu + ((u >> 16) & 1u)) >> 16;
  return (unsigned short)u;
}

__device__ __forceinline__ void xp_store(float* p, float v) { *p = v; }
__device__ __forceinline__ void xp_store(unsigned short* p, float v) { *p = f2bf(v); }
__device__ __forceinline__ float xp_load(const float* p) { return *p; }
__device__ __forceinline__ float xp_load(const unsigned short* p) {
  return __uint_as_float(((unsigned int)*p) << 16);
}

// ---------------- prep: pack W_x and W_h (f32 -> bf16 pairs) ----------------
__global__ void prep_wx(const float* __restrict__ W, unsigned int* __restrict__ Wx2) {
  int i = blockIdx.x * 256 + threadIdx.x;  // 1024*128 dwords
  int g = i >> 7, kk = i & 127;
  float lo = W[(size_t)g * 512 + 256 + 2 * kk];
  float hi = W[(size_t)g * 512 + 256 + 2 * kk + 1];
  Wx2[i] = (unsigned int)f2bf(lo) | ((unsigned int)f2bf(hi) << 16);
}

__global__ void prep_wh(const float* __restrict__ W, unsigned int* __restrict__ Wh2) {
  int i = blockIdx.x * 256 + threadIdx.x;  // 1024*128 dwords
  int r = i >> 7, kk = i & 127;
  float lo = W[(size_t)r * 512 + 2 * kk];
  float hi = W[(size_t)r * 512 + 2 * kk + 1];
  Wh2[i] = (unsigned int)f2bf(lo) | ((unsigned int)f2bf(hi) << 16);
}

// ---------------- GEMM: xp[m][g] = sum_k x[m][k] * Wx[g][k] + b[g] ----------------
template <typename XPT>
__global__ __launch_bounds__(256, 4) void gemm_xp(const float* __restrict__ x,
                                                  const unsigned int* __restrict__ Wx2,
                                                  const float* __restrict__ bias,
                                                  XPT* __restrict__ xp) {
  __shared__ unsigned short As[128][40];
  __shared__ unsigned short Bs[128][40];
  const int m0 = blockIdx.y * 128, n0 = blockIdx.x * 128;
  const int tid = threadIdx.x, lane = tid & 63, w = tid >> 6;
  const int wr = w >> 1, wc = w & 1;
  const int r16 = lane & 15, kq = lane >> 4;
  f32x4 acc[4][4];
#pragma unroll
  for (int m = 0; m < 4; m++)
#pragma unroll
    for (int n = 0; n < 4; n++)
#pragma unroll
      for (int j = 0; j < 4; j++) acc[m][n][j] = 0.f;

  for (int kb = 0; kb < 256; kb += 32) {
    __syncthreads();
#pragma unroll
    for (int i = 0; i < 4; i++) {
      int idx = tid + i * 256;
      int row = idx >> 3, c4 = idx & 7;
      float4 v = *(const float4*)(x + (size_t)(m0 + row) * 256 + kb + c4 * 4);
      ushort4 s;
      s.x = f2bf(v.x); s.y = f2bf(v.y); s.z = f2bf(v.z); s.w = f2bf(v.w);
      *(ushort4*)&As[row][c4 * 4] = s;
    }
#pragma unroll
    for (int i = 0; i < 2; i++) {
      int idx = tid + i * 256;
      int row = idx >> 2, c = idx & 3;
      uint4 v = *(const uint4*)(Wx2 + (size_t)(n0 + row) * 128 + (kb >> 1) + c * 4);
      *(uint4*)&Bs[row][c * 8] = v;
    }
    __syncthreads();
    short8 a[4], bb[4];
#pragma unroll
    for (int m = 0; m < 4; m++)
      a[m] = *(const short8*)&As[wr * 64 + m * 16 + r16][kq * 8];
#pragma unroll
    for (int n = 0; n < 4; n++)
      bb[n] = *(const short8*)&Bs[wc * 64 + n * 16 + r16][kq * 8];
#pragma unroll
    for (int m = 0; m < 4; m++)
#pragma unroll
      for (int n = 0; n < 4; n++)
        acc[m][n] = __builtin_amdgcn_mfma_f32_16x16x32_bf16(a[m], bb[n], acc[m][n], 0, 0, 0);
  }
#pragma unroll
  for (int n = 0; n < 4; n++) {
    int gn = n0 + wc * 64 + n * 16 + r16;
    float bi = bias[gn];
#pragma unroll
    for (int m = 0; m < 4; m++) {
      int gm = m0 + wr * 64 + m * 16 + kq * 4;
#pragma unroll
      for (int j = 0; j < 4; j++) {
        xp_store(&xp[(size_t)(gm + j) * 1024 + gn], acc[m][n][j] + bi);
      }
    }
  }
}

// ---------------- recurrence: ONE BATCH PER CU, LDS-only h exchange ----------------
// 64 WGs x 1024 threads (16 waves/CU). Thread (u = tid>>2, p = tid&3) owns unit u's
// four gate rows over k-slice [p*64, p*64+64). Weights bf16-packed: rows f,i,g in 24
// named u32x4 VGPR values (96 dwords); row o in LDS (1024 chunks x 32 dwords + 4 pad
// -> lane stride 36 dw = 4 mod 32 banks: b128 reads at the bandwidth floor, no
// conflicts). h state: 128 bf16-pair dwords in LDS, double-buffered; reads are
// same-address broadcasts across the 4 p-groups. Dot via v_dot2_f32_bf16 (2 MACs/
// inst). Reduce across p: 2-round __shfl_xor. ONE __syncthreads per step; no
// inter-WG traffic at all (R1-R7 lesson: the MALL exchange floor is ~4us/step).
template <typename XPT>
__global__ __launch_bounds__(1024, 4) void lstm_rec(const unsigned* __restrict__ Wh2,
                                                    const XPT* __restrict__ xp,
                                                    float* __restrict__ out) {
  __shared__ unsigned wo[1024 * 36];  // 144KB: o-row slices, padded
  __shared__ unsigned hb2[2][128];    // h as bf16 pairs, double-buffered

  const int tid = threadIdx.x;
  const int b = blockIdx.x;
  const int u = tid >> 2, p = tid & 3;

  // ---- init: f,i,g weight slices into 24 named register vectors (96 VGPRs)
  const unsigned* wf_p = Wh2 + (size_t)(0 * 256 + u) * 128 + (p << 5);
  const unsigned* wi_p = Wh2 + (size_t)(1 * 256 + u) * 128 + (p << 5);
  const unsigned* wg_p = Wh2 + (size_t)(2 * 256 + u) * 128 + (p << 5);
  const unsigned* wo_p = Wh2 + (size_t)(3 * 256 + u) * 128 + (p << 5);
  u32x4 wf0 = *(const u32x4*)(wf_p + 0),  wf1 = *(const u32x4*)(wf_p + 4);
  u32x4 wf2 = *(const u32x4*)(wf_p + 8),  wf3 = *(const u32x4*)(wf_p + 12);
  u32x4 wf4 = *(const u32x4*)(wf_p + 16), wf5 = *(const u32x4*)(wf_p + 20);
  u32x4 wf6 = *(const u32x4*)(wf_p + 24), wf7 = *(const u32x4*)(wf_p + 28);
  u32x4 wi0 = *(const u32x4*)(wi_p + 0),  wi1 = *(const u32x4*)(wi_p + 4);
  u32x4 wi2 = *(const u32x4*)(wi_p + 8),  wi3 = *(const u32x4*)(wi_p + 12);
  u32x4 wi4 = *(const u32x4*)(wi_p + 16), wi5 = *(const u32x4*)(wi_p + 20);
  u32x4 wi6 = *(const u32x4*)(wi_p + 24), wi7 = *(const u32x4*)(wi_p + 28);
  u32x4 wg0 = *(const u32x4*)(wg_p + 0),  wg1 = *(const u32x4*)(wg_p + 4);
  u32x4 wg2 = *(const u32x4*)(wg_p + 8),  wg3 = *(const u32x4*)(wg_p + 12);
  u32x4 wg4 = *(const u32x4*)(wg_p + 16), wg5 = *(const u32x4*)(wg_p + 20);
  u32x4 wg6 = *(const u32x4*)(wg_p + 24), wg7 = *(const u32x4*)(wg_p + 28);

  // ---- o-row slice into LDS (32 dwords at chunk tid*36)
#pragma unroll
  for (int j = 0; j < 8; j++) {
    u32x4 v = *(const u32x4*)(wo_p + (j << 2));
    *(u32x4*)&wo[tid * 36 + (j << 2)] = v;
  }
  // ---- h buffers: zero both slots
  if (tid < 256) ((unsigned*)hb2)[tid] = 0u;

  const size_t xpb = (size_t)b << 10;
  float xv0, xv1, xv2, xv3;
  {
    const XPT* xr = &xp[xpb * 1024 + u];
    xv0 = xp_load(xr); xv1 = xp_load(xr + 256);
    xv2 = xp_load(xr + 512); xv3 = xp_load(xr + 768);
  }
  float c = 0.f;
  __syncthreads();

  for (int t = 0; t < 1024; t++) {
    const unsigned* hrow = &hb2[(t + 1) & 1][p << 5];  // (t-1)&1 == (t+1)&1
    const unsigned* orow = &wo[tid * 36];

    float a0 = 0.f, a1 = 0.f, a2 = 0.f, a3 = 0.f;
#define DOT2(ACC, WD, HD) \
  asm("v_dot2_f32_bf16 %0, %1, %2, %0" : "+v"(ACC) : "v"(WD), "v"(HD))
#define STEPJ(J, WF, WI, WG)                                   \
  {                                                            \
    u32x4 hj = *(const u32x4*)(hrow + (J << 2));               \
    u32x4 oj = *(const u32x4*)(orow + (J << 2));               \
    DOT2(a0, WF[0], hj[0]); DOT2(a0, WF[1], hj[1]);            \
    DOT2(a0, WF[2], hj[2]); DOT2(a0, WF[3], hj[3]);            \
    DOT2(a1, WI[0], hj[0]); DOT2(a1, WI[1], hj[1]);            \
    DOT2(a1, WI[2], hj[2]); DOT2(a1, WI[3], hj[3]);            \
    DOT2(a2, WG[0], hj[0]); DOT2(a2, WG[1], hj[1]);            \
    DOT2(a2, WG[2], hj[2]); DOT2(a2, WG[3], hj[3]);            \
    DOT2(a3, oj[0], hj[0]); DOT2(a3, oj[1], hj[1]);            \
    DOT2(a3, oj[2], hj[2]); DOT2(a3, oj[3], hj[3]);            \
  }
    STEPJ(0, wf0, wi0, wg0) STEPJ(1, wf1, wi1, wg1)
    STEPJ(2, wf2, wi2, wg2) STEPJ(3, wf3, wi3, wg3)
    STEPJ(4, wf4, wi4, wg4) STEPJ(5, wf5, wi5, wg5)
    STEPJ(6, wf6, wi6, wg6) STEPJ(7, wf7, wi7, wg7)
#undef STEPJ
#undef DOT2

    // reduce over the 4 p-lanes (adjacent lanes)
    a0 += __shfl_xor(a0, 1, 64); a0 += __shfl_xor(a0, 2, 64);
    a1 += __shfl_xor(a1, 1, 64); a1 += __shfl_xor(a1, 2, 64);
    a2 += __shfl_xor(a2, 1, 64); a2 += __shfl_xor(a2, 2, 64);
    a3 += __shfl_xor(a3, 1, 64); a3 += __shfl_xor(a3, 2, 64);

    float gf = a0 + xv0, gi = a1 + xv1, gg = a2 + xv2, go = a3 + xv3;
    float f = 1.f / (1.f + __expf(-gf));
    float ii = 1.f / (1.f + __expf(-gi));
    float eg = __expf(2.f * gg);
    float gt = (eg - 1.f) / (eg + 1.f);
    float o = 1.f / (1.f + __expf(-go));
    c = f * c + ii * gt;
    float ec = __expf(2.f * c);
    float tc = (ec - 1.f) / (ec + 1.f);
    float h = o * tc;

    // publish h: even-u p0 lanes pack (h[u], h[u+1]) into one bf16-pair dword
    float hu1 = __shfl(h, (tid & 63) + 4, 64);  // partner unit's h (garbage for odd u)
    if (p == 0) {
      __builtin_nontemporal_store(h, &out[(xpb + t) * 256 + u]);
      if ((u & 1) == 0) {
        unsigned dw = (unsigned)f2bf(h) | ((unsigned)f2bf(hu1) << 16);
        hb2[t & 1][u >> 1] = dw;
      }
    }

    if (t < 1023) {
      const XPT* xr = &xp[(xpb + t + 1) * 1024 + u];
      xv0 = xp_load(xr); xv1 = xp_load(xr + 256);
      xv2 = xp_load(xr + 512); xv3 = xp_load(xr + 768);
    } else if (p == 0) {
      out[16777216 + b * 256 + u] = h;           // h_fin
      out[16777216 + 16384 + b * 256 + u] = c;   // c_fin
    }
    __syncthreads();
  }
}

extern "C" void kernel_launch(void* const* d_in, const int* in_sizes, int n_in,
                              void* d_out, int out_size, void* d_ws, size_t ws_size,
                              hipStream_t stream) {
  (void)in_sizes; (void)n_in; (void)out_size;
  const float* x = (const float*)d_in[0];
  const float* W = (const float*)d_in[1];
  const float* bias = (const float*)d_in[2];
  float* out = (float*)d_out;
  char* ws = (char*)d_ws;

  unsigned int* Wx2 = (unsigned int*)ws;              // 524288 B
  unsigned int* Wh2 = (unsigned int*)(ws + 524288);   // 524288 B
  char* xpmem = ws + 1048576;

  const size_t need32 = 1048576 + (size_t)65536 * 1024 * 4;

  prep_wx<<<512, 256, 0, stream>>>(W, Wx2);
  prep_wh<<<512, 256, 0, stream>>>(W, Wh2);

  if (ws_size >= need32) {
    gemm_xp<float><<<dim3(8, 512), 256, 0, stream>>>(x, Wx2, bias, (float*)xpmem);
    lstm_rec<float><<<64, 1024, 0, stream>>>(Wh2, (const float*)xpmem, out);
  } else {
    gemm_xp<unsigned short><<<dim3(8, 512), 256, 0, stream>>>(x, Wx2, bias,
                                                              (unsigned short*)xpmem);
    lstm_rec<unsigned short><<<64, 1024, 0, stream>>>(Wh2, (const unsigned short*)xpmem, out);
  }
}